// Round 12
// baseline (440.492 us; speedup 1.0000x reference)
//
#include <hip/hip_runtime.h>
#include <hip/hip_bf16.h>
#include <stdint.h>

#define S_LEN 2048
#define NB 2
#define NH 16
#define DM 1024
#define KDIM 64
#define MTOK (NB*S_LEN)   // 4096 tokens

typedef __attribute__((ext_vector_type(8))) short bf16x8;
typedef __attribute__((ext_vector_type(4))) float f32x4;
typedef __attribute__((ext_vector_type(4))) unsigned short u16x4;
typedef __attribute__((ext_vector_type(8))) unsigned short u16x8;

#define AS1 __attribute__((address_space(1)))
#define AS3 __attribute__((address_space(3)))

__device__ __forceinline__ unsigned short f2bf(float f) {
  unsigned int u = __builtin_bit_cast(unsigned int, f);
  return (unsigned short)((u + 0x7fffu + ((u >> 16) & 1u)) >> 16);   // RNE
}
__device__ __forceinline__ float bf2f(unsigned short h) {
  unsigned int u = ((unsigned int)h) << 16;
  return __builtin_bit_cast(float, u);
}
__device__ __forceinline__ f32x4 mfma16(bf16x8 a, bf16x8 b, f32x4 c) {
  return __builtin_amdgcn_mfma_f32_16x16x32_bf16(a, b, c, 0, 0, 0);
}

// ---------------------------------------------------------------------------
// fp32 -> bf16 convert, 7 segments
// ---------------------------------------------------------------------------
struct CvtArgs {
  const float* src[7];
  unsigned short* dst[7];
  int n[7];
};

__global__ __launch_bounds__(256) void cvt_f32_bf16(CvtArgs a) {
  const int seg = blockIdx.y;
  const float* __restrict__ s = a.src[seg];
  unsigned short* __restrict__ d = a.dst[seg];
  const int n4 = a.n[seg] >> 2;
  const int stride = gridDim.x * blockDim.x;
  for (int i = blockIdx.x * blockDim.x + threadIdx.x; i < n4; i += stride) {
    const float4 v = reinterpret_cast<const float4*>(s)[i];
    u16x4 o;
    o[0] = f2bf(v.x); o[1] = f2bf(v.y); o[2] = f2bf(v.z); o[3] = f2bf(v.w);
    reinterpret_cast<u16x4*>(d)[i] = o;
  }
}

// ---------------------------------------------------------------------------
// Pipelined GEMM (R9-verified) + XCD-local m-tile remap (R11).
// ---------------------------------------------------------------------------
struct GemmArgs {
  const unsigned short* A[3];
  const unsigned short* W[3];
  const float* bias[3];
  void* dst[3];
  int mode[3];
};

__global__ __launch_bounds__(256, 2)
void gemm_pipe(GemmArgs ga)
{
  __shared__ __align__(16) char smem[32768];   // 2 x (A 8K + B 8K); Cs union

  const int z = blockIdx.z;
  const unsigned short* __restrict__ A  = ga.A[z];
  const unsigned short* __restrict__ Bw = ga.W[z];
  const float* __restrict__ bias = ga.bias[z];
  void* __restrict__ dst = ga.dst[z];
  const int mode = ga.mode[z];

  const int t = threadIdx.x;
  const int w = t >> 6, l = t & 63;
  const int g = l >> 4, cl = l & 15;

  const int L   = blockIdx.x + 8 * blockIdx.y;   // 0..255
  const int xcd = L & 7, ix = L >> 3;
  const int m0  = (xcd * 4 + (ix & 3)) * 128;
  const int n0  = (ix >> 2) * 128;

  const unsigned short* Ag = A  + (size_t)(m0 + (t >> 2)) * DM + (t & 3) * 8;
  const unsigned short* Bg = Bw + (size_t)(n0 + (t >> 2)) * DM + (t & 3) * 8;

  const int wm = (w >> 1) * 64, wn = (w & 1) * 64;

  f32x4 acc[4][4];
  #pragma unroll
  for (int i = 0; i < 4; ++i)
    #pragma unroll
    for (int j = 0; j < 4; ++j) acc[i][j] = 0.f;

  #define STAGE(step) do {                                                          \
    AS3 char* _buf = (AS3 char*)smem + ((step) & 1) * 16384;                         \
    __builtin_amdgcn_global_load_lds((const AS1 void*)(Ag + (step)*32),              \
                                     (AS3 void*)(_buf + w*1024),          16, 0, 0); \
    __builtin_amdgcn_global_load_lds((const AS1 void*)(Ag + (step)*32 + 64*DM),      \
                                     (AS3 void*)(_buf + 4096 + w*1024),   16, 0, 0); \
    __builtin_amdgcn_global_load_lds((const AS1 void*)(Bg + (step)*32),              \
                                     (AS3 void*)(_buf + 8192 + w*1024),   16, 0, 0); \
    __builtin_amdgcn_global_load_lds((const AS1 void*)(Bg + (step)*32 + 64*DM),      \
                                     (AS3 void*)(_buf + 12288 + w*1024),  16, 0, 0); \
  } while (0)

  STAGE(0);
  for (int s = 0; s < 32; ++s) {
    if (s < 31) {
      STAGE(s + 1);
      asm volatile("s_waitcnt vmcnt(4)" ::: "memory");
    } else {
      asm volatile("s_waitcnt vmcnt(0)" ::: "memory");
    }
    __builtin_amdgcn_s_barrier();
    __builtin_amdgcn_sched_barrier(0);

    const AS3 unsigned short* bufA =
        (const AS3 unsigned short*)((AS3 char*)smem + (s & 1) * 16384);
    const AS3 unsigned short* bufB = bufA + 4096;
    bf16x8 af[4], bfv[4];
    #pragma unroll
    for (int i = 0; i < 4; ++i)
      af[i] = *(const AS3 bf16x8*)(bufA + (wm + 16*i + cl) * 32 + g*8);
    #pragma unroll
    for (int j = 0; j < 4; ++j)
      bfv[j] = *(const AS3 bf16x8*)(bufB + (wn + 16*j + cl) * 32 + g*8);
    #pragma unroll
    for (int i = 0; i < 4; ++i)
      #pragma unroll
      for (int j = 0; j < 4; ++j)
        acc[i][j] = mfma16(af[i], bfv[j], acc[i][j]);

    __builtin_amdgcn_sched_barrier(0);
    __builtin_amdgcn_s_barrier();
  }
  #undef STAGE

  if (mode == 1) {
    unsigned short* Cs = (unsigned short*)smem;
    __syncthreads();
    #pragma unroll
    for (int i = 0; i < 4; ++i) {
      #pragma unroll
      for (int j = 0; j < 4; ++j) {
        const int n = wn + 16*j + cl;
        const float bn = bias[n0 + n];
        const int u = (wm >> 2) + 4*i + g;
        const int us = u ^ (n & 31);
        u16x4 o;
        #pragma unroll
        for (int r = 0; r < 4; ++r) o[r] = f2bf(acc[i][j][r] + bn);
        *reinterpret_cast<u16x4*>(&Cs[n*128 + us*4]) = o;
      }
    }
    __syncthreads();
    {
      const int n = t >> 1, mh = (t & 1) * 64;
      const int ncol = n0 + n;
      const int h = ncol >> 6, d = ncol & (KDIM-1);
      const int b = m0 >> 11, s0 = m0 & (S_LEN-1);
      unsigned short* drow = (unsigned short*)dst
          + ((size_t)(b*NH + h)*KDIM + d)*S_LEN + s0 + mh;
      #pragma unroll
      for (int mm = 0; mm < 4; ++mm) {
        u16x4 v[4];
        #pragma unroll
        for (int k = 0; k < 4; ++k) {
          const int us = ((mh >> 2) + mm*4 + k) ^ (n & 31);
          v[k] = *reinterpret_cast<const u16x4*>(&Cs[n*128 + us*4]);
        }
        u16x8 w01, w23;
        #pragma unroll
        for (int e = 0; e < 4; ++e) {
          w01[e] = v[0][e]; w01[4+e] = v[1][e];
          w23[e] = v[2][e]; w23[4+e] = v[3][e];
        }
        *reinterpret_cast<u16x8*>(drow + mm*16)     = w01;
        *reinterpret_cast<u16x8*>(drow + mm*16 + 8) = w23;
      }
    }
  } else {
    #pragma unroll
    for (int i = 0; i < 4; ++i)
      #pragma unroll
      for (int j = 0; j < 4; ++j) {
        const int ncol = n0 + wn + 16*j + cl;
        const float bn = bias[ncol];
        #pragma unroll
        for (int r = 0; r < 4; ++r) {
          const int m = m0 + wm + 16*i + g*4 + r;
          const float v = acc[i][j][r] + bn;
          if (mode == 0) {
            const int b = m >> 11, sR = m & (S_LEN-1);
            const int h = ncol >> 6, d = ncol & (KDIM-1);
            ((unsigned short*)dst)[((size_t)(b*NH + h)*S_LEN + sR)*KDIM + d] = f2bf(v);
          } else {
            ((float*)dst)[(size_t)m * DM + ncol] = v;
          }
        }
      }
  }
}

// ---------------------------------------------------------------------------
// attn_reg: ONE QK^T pass, P kept in registers (16 q x 256 kv per wave =
// 32 VGPR packed bf16). Block = 16 q-rows, 8 waves x 256-kv strips, 4096
// blocks (XCD-swizzled). Phases: QK^T (global K, 2-deep prefetch, no LDS,
// no barriers) -> sum combine (1 barrier) -> PV (LDS bounce + global V) ->
// O reduce (LDS atomics, 1 barrier) -> ctx -> PURE attn store tail (no
// loads, no waits after).
// ---------------------------------------------------------------------------
__global__ __launch_bounds__(512, 4)
void attn_reg(const unsigned short* __restrict__ Qh,
              const unsigned short* __restrict__ Kh,
              const unsigned short* __restrict__ Vt,
              float* __restrict__ attn,
              unsigned short* __restrict__ ctx)
{
  __shared__ float statL[8][16];
  __shared__ float Obuf[16][68];                 // atomic O accum (padded)
  __shared__ __align__(16) char PB[8][1280];     // per-wave P bounce, 80B rows

  const int id  = blockIdx.x;                    // 4096 = 8 * 512
  const int swz = (id & 7) * 512 + (id >> 3);    // bijective XCD swizzle
  const int bh  = swz >> 7;                      // 0..31  (= b*16 + h)
  const int q0  = (swz & 127) * 16;              // q-tile base

  const int t = threadIdx.x, w = t >> 6, l = t & 63;
  const int g = l >> 4, cl = l & 15;
  const int kv0 = w * 256;

  for (int i = t; i < 16 * 68; i += 512) (&Obuf[0][0])[i] = 0.f;

  const unsigned short* Qb = Qh + ((size_t)bh * S_LEN + q0 + cl) * KDIM;
  const bf16x8 qf0 = *reinterpret_cast<const bf16x8*>(Qb + g*8);
  const bf16x8 qf1 = *reinterpret_cast<const bf16x8*>(Qb + 32 + g*8);

  const unsigned short* Kit = Kh + (size_t)bh*S_LEN*KDIM
                                 + (size_t)(kv0 + cl)*KDIM + g*8;
  const float SC2 = 0.125f * 1.44269504f;        // 1/sqrt(64) * log2(e)

  // ---- phase 1: QK^T over own strip; P -> registers; partial sums ----
  bf16x8 kA0 = *reinterpret_cast<const bf16x8*>(Kit);
  bf16x8 kA1 = *reinterpret_cast<const bf16x8*>(Kit + 32);
  bf16x8 kB0 = *reinterpret_cast<const bf16x8*>(Kit + 16*KDIM);
  bf16x8 kB1 = *reinterpret_cast<const bf16x8*>(Kit + 16*KDIM + 32);

  u16x4 p[16];
  float sa0 = 0.f, sa1 = 0.f, sa2 = 0.f, sa3 = 0.f;
  #pragma unroll
  for (int s = 0; s < 16; ++s) {
    const bf16x8 k0 = kA0, k1 = kA1;
    kA0 = kB0; kA1 = kB1;
    const unsigned short* nxt = Kit + (size_t)(s + 2) * 16 * KDIM;  // ws slack
    kB0 = *reinterpret_cast<const bf16x8*>(nxt);
    kB1 = *reinterpret_cast<const bf16x8*>(nxt + 32);
    f32x4 acc = {0.f, 0.f, 0.f, 0.f};
    acc = mfma16(k0, qf0, acc);
    acc = mfma16(k1, qf1, acc);
    const float p0 = __builtin_exp2f(acc[0] * SC2);
    const float p1 = __builtin_exp2f(acc[1] * SC2);
    const float p2 = __builtin_exp2f(acc[2] * SC2);
    const float p3 = __builtin_exp2f(acc[3] * SC2);
    sa0 += p0; sa1 += p1; sa2 += p2; sa3 += p3;
    u16x4 pb;
    pb[0] = f2bf(p0); pb[1] = f2bf(p1); pb[2] = f2bf(p2); pb[3] = f2bf(p3);
    p[s] = pb;
  }

  float ssum = (sa0 + sa1) + (sa2 + sa3);
  ssum += __shfl_xor(ssum, 16, 64);
  ssum += __shfl_xor(ssum, 32, 64);              // strip sum for row q=cl
  if (l < 16) statL[w][l] = ssum;
  __syncthreads();                               // statL + Obuf init ready

  float inv;                                      // row q=cl total inverse
  {
    float s0 = statL[0][cl] + statL[1][cl] + statL[2][cl] + statL[3][cl];
    float s1 = statL[4][cl] + statL[5][cl] + statL[6][cl] + statL[7][cl];
    inv = 1.0f / (s0 + s1);
  }

  // ---- phase 2: PV over own strip (8 chunks of 32 kv), V 1-chunk prefetch --
  AS3 char* const PBw = (AS3 char*)&PB[w][0];
  const unsigned short* Vb = Vt + (size_t)bh*KDIM*S_LEN + kv0;

  bf16x8 vp0, vp1, vp2, vp3;
  {
    const unsigned short* Vp = Vb + (size_t)cl * S_LEN + g*8;
    vp0 = *reinterpret_cast<const bf16x8*>(Vp);
    vp1 = *reinterpret_cast<const bf16x8*>(Vp + 16 * S_LEN);
    vp2 = *reinterpret_cast<const bf16x8*>(Vp + 32 * S_LEN);
    vp3 = *reinterpret_cast<const bf16x8*>(Vp + 48 * S_LEN);
  }

  f32x4 accP[4];
  #pragma unroll
  for (int dt = 0; dt < 4; ++dt) accP[dt] = 0.f;

  #pragma unroll
  for (int ch = 0; ch < 8; ++ch) {
    *(AS3 u16x4*)(PBw + cl*80 + g*8)      = p[2*ch];
    *(AS3 u16x4*)(PBw + cl*80 + 32 + g*8) = p[2*ch + 1];
    const bf16x8 v0 = vp0, v1 = vp1, v2 = vp2, v3 = vp3;
    {  // prefetch next chunk (overrun lands in allocated ws)
      const unsigned short* Vp = Vb + (size_t)cl * S_LEN + (ch + 1)*32 + g*8;
      vp0 = *reinterpret_cast<const bf16x8*>(Vp);
      vp1 = *reinterpret_cast<const bf16x8*>(Vp + 16 * S_LEN);
      vp2 = *reinterpret_cast<const bf16x8*>(Vp + 32 * S_LEN);
      vp3 = *reinterpret_cast<const bf16x8*>(Vp + 48 * S_LEN);
    }
    const bf16x8 ap = *(const AS3 bf16x8*)(PBw + cl*80 + g*16);
    accP[0] = mfma16(ap, v0, accP[0]);
    accP[1] = mfma16(ap, v1, accP[1]);
    accP[2] = mfma16(ap, v2, accP[2]);
    accP[3] = mfma16(ap, v3, accP[3]);
  }

  // normalized O partials -> Obuf via LDS atomics (q = g*4+r, d = dt*16+cl)
  #pragma unroll
  for (int r = 0; r < 4; ++r) {
    const float invq = __shfl(inv, g*4 + r, 64);
    #pragma unroll
    for (int dt = 0; dt < 4; ++dt)
      atomicAdd(&Obuf[g*4 + r][dt*16 + cl], accP[dt][r] * invq);
  }
  __syncthreads();                               // Obuf complete

  // ---- ctx write (first 256 threads) ----
  if (t < 256) {
    const int b = bh >> 4, h = bh & 15;
    const int q = t >> 4, d0 = (t & 15) * 4;
    u16x4 o;
    o[0] = f2bf(Obuf[q][d0 + 0]);
    o[1] = f2bf(Obuf[q][d0 + 1]);
    o[2] = f2bf(Obuf[q][d0 + 2]);
    o[3] = f2bf(Obuf[q][d0 + 3]);
    *reinterpret_cast<u16x4*>(
        ctx + ((size_t)(b * S_LEN + q0 + q)) * DM + h * KDIM + d0) = o;
  }

  // ---- phase 3: pure attn store tail (no loads, no waits after) ----
  float* const arow = attn + ((size_t)bh * S_LEN + q0 + cl) * S_LEN + kv0 + g*4;
  #pragma unroll
  for (int s = 0; s < 16; ++s) {
    f32x4 o;
    o[0] = bf2f((unsigned short)p[s][0]) * inv;
    o[1] = bf2f((unsigned short)p[s][1]) * inv;
    o[2] = bf2f((unsigned short)p[s][2]) * inv;
    o[3] = bf2f((unsigned short)p[s][3]) * inv;
    *reinterpret_cast<f32x4*>(arow + s*16) = o;
  }
}

// ---------------------------------------------------------------------------
extern "C" void kernel_launch(void* const* d_in, const int* in_sizes, int n_in,
                              void* d_out, int out_size, void* d_ws, size_t ws_size,
                              hipStream_t stream)
{
  const float* q_in = (const float*)d_in[0];
  const float* k_in = (const float*)d_in[1];
  const float* v_in = (const float*)d_in[2];
  const float* Wq   = (const float*)d_in[3];
  const float* bq   = (const float*)d_in[4];
  const float* Wk   = (const float*)d_in[5];
  const float* bk   = (const float*)d_in[6];
  const float* Wv   = (const float*)d_in[7];
  const float* bv   = (const float*)d_in[8];
  const float* Wo   = (const float*)d_in[9];
  const float* bo   = (const float*)d_in[10];

  unsigned short* qbf  = (unsigned short*)d_ws;
  unsigned short* kbf  = qbf  + (size_t)MTOK*DM;
  unsigned short* vbf  = kbf  + (size_t)MTOK*DM;
  unsigned short* wqbf = vbf  + (size_t)MTOK*DM;
  unsigned short* wkbf = wqbf + (size_t)DM*DM;
  unsigned short* wvbf = wkbf + (size_t)DM*DM;
  unsigned short* wobf = wvbf + (size_t)DM*DM;
  unsigned short* Qhp  = wobf + (size_t)DM*DM;    // [b,h,s,d]
  unsigned short* Khp  = Qhp  + (size_t)MTOK*DM;  // [b,h,s,d]
  unsigned short* Vtp  = Khp  + (size_t)MTOK*DM;  // [b,h,d,s]
  unsigned short* ctx  = Vtp  + (size_t)MTOK*DM;  // [b*s, h*d]

  float* out0 = (float*)d_out;
  float* attn = out0 + (size_t)MTOK*DM;

  CvtArgs ca;
  ca.src[0] = q_in; ca.dst[0] = qbf;  ca.n[0] = MTOK*DM;
  ca.src[1] = k_in; ca.dst[1] = kbf;  ca.n[1] = MTOK*DM;
  ca.src[2] = v_in; ca.dst[2] = vbf;  ca.n[2] = MTOK*DM;
  ca.src[3] = Wq;   ca.dst[3] = wqbf; ca.n[3] = DM*DM;
  ca.src[4] = Wk;   ca.dst[4] = wkbf; ca.n[4] = DM*DM;
  ca.src[5] = Wv;   ca.dst[5] = wvbf; ca.n[5] = DM*DM;
  ca.src[6] = Wo;   ca.dst[6] = wobf; ca.n[6] = DM*DM;
  cvt_f32_bf16<<<dim3(512, 7), 256, 0, stream>>>(ca);

  GemmArgs gq;
  gq.A[0] = qbf;  gq.W[0] = wqbf; gq.bias[0] = bq; gq.dst[0] = Qhp; gq.mode[0] = 0;
  gq.A[1] = kbf;  gq.W[1] = wkbf; gq.bias[1] = bk; gq.dst[1] = Khp; gq.mode[1] = 0;
  gq.A[2] = vbf;  gq.W[2] = wvbf; gq.bias[2] = bv; gq.dst[2] = Vtp; gq.mode[2] = 1;
  gemm_pipe<<<dim3(8, 32, 3), 256, 0, stream>>>(gq);

  attn_reg<<<dim3(4096), 512, 0, stream>>>(Qhp, Khp, Vtp, attn, ctx);

  GemmArgs go;
  go.A[0] = ctx; go.W[0] = wobf; go.bias[0] = bo; go.dst[0] = out0; go.mode[0] = 2;
  gemm_pipe<<<dim3(8, 32, 1), 256, 0, stream>>>(go);
}

// Round 13
// 278.062 us; speedup vs baseline: 1.5842x; 1.5842x over previous
//
#include <hip/hip_runtime.h>
#include <hip/hip_bf16.h>
#include <stdint.h>

#define S_LEN 2048
#define NB 2
#define NH 16
#define DM 1024
#define KDIM 64
#define MTOK (NB*S_LEN)   // 4096 tokens

typedef __attribute__((ext_vector_type(8))) short bf16x8;
typedef __attribute__((ext_vector_type(4))) float f32x4;
typedef __attribute__((ext_vector_type(4))) unsigned short u16x4;
typedef __attribute__((ext_vector_type(8))) unsigned short u16x8;

#define AS1 __attribute__((address_space(1)))
#define AS3 __attribute__((address_space(3)))

__device__ __forceinline__ unsigned short f2bf(float f) {
  unsigned int u = __builtin_bit_cast(unsigned int, f);
  return (unsigned short)((u + 0x7fffu + ((u >> 16) & 1u)) >> 16);   // RNE
}
__device__ __forceinline__ f32x4 mfma16(bf16x8 a, bf16x8 b, f32x4 c) {
  return __builtin_amdgcn_mfma_f32_16x16x32_bf16(a, b, c, 0, 0, 0);
}

// ---------------------------------------------------------------------------
// fp32 -> bf16 convert, 7 segments
// ---------------------------------------------------------------------------
struct CvtArgs {
  const float* src[7];
  unsigned short* dst[7];
  int n[7];
};

__global__ __launch_bounds__(256) void cvt_f32_bf16(CvtArgs a) {
  const int seg = blockIdx.y;
  const float* __restrict__ s = a.src[seg];
  unsigned short* __restrict__ d = a.dst[seg];
  const int n4 = a.n[seg] >> 2;
  const int stride = gridDim.x * blockDim.x;
  for (int i = blockIdx.x * blockDim.x + threadIdx.x; i < n4; i += stride) {
    const float4 v = reinterpret_cast<const float4*>(s)[i];
    u16x4 o;
    o[0] = f2bf(v.x); o[1] = f2bf(v.y); o[2] = f2bf(v.z); o[3] = f2bf(v.w);
    reinterpret_cast<u16x4*>(d)[i] = o;
  }
}

// ---------------------------------------------------------------------------
// Pipelined GEMM (R9-verified) + XCD-local m-tile remap: XCD k owns m-tiles
// [4k,4k+4) x all 8 n-tiles -> A-panels fetched once per XCD L2.
// ---------------------------------------------------------------------------
struct GemmArgs {
  const unsigned short* A[3];
  const unsigned short* W[3];
  const float* bias[3];
  void* dst[3];
  int mode[3];
};

__global__ __launch_bounds__(256, 2)
void gemm_pipe(GemmArgs ga)
{
  __shared__ __align__(16) char smem[32768];   // 2 x (A 8K + B 8K); Cs union

  const int z = blockIdx.z;
  const unsigned short* __restrict__ A  = ga.A[z];
  const unsigned short* __restrict__ Bw = ga.W[z];
  const float* __restrict__ bias = ga.bias[z];
  void* __restrict__ dst = ga.dst[z];
  const int mode = ga.mode[z];

  const int t = threadIdx.x;
  const int w = t >> 6, l = t & 63;
  const int g = l >> 4, cl = l & 15;

  const int L   = blockIdx.x + 8 * blockIdx.y;   // 0..255
  const int xcd = L & 7, ix = L >> 3;
  const int m0  = (xcd * 4 + (ix & 3)) * 128;
  const int n0  = (ix >> 2) * 128;

  const unsigned short* Ag = A  + (size_t)(m0 + (t >> 2)) * DM + (t & 3) * 8;
  const unsigned short* Bg = Bw + (size_t)(n0 + (t >> 2)) * DM + (t & 3) * 8;

  const int wm = (w >> 1) * 64, wn = (w & 1) * 64;

  f32x4 acc[4][4];
  #pragma unroll
  for (int i = 0; i < 4; ++i)
    #pragma unroll
    for (int j = 0; j < 4; ++j) acc[i][j] = 0.f;

  #define STAGE(step) do {                                                          \
    AS3 char* _buf = (AS3 char*)smem + ((step) & 1) * 16384;                         \
    __builtin_amdgcn_global_load_lds((const AS1 void*)(Ag + (step)*32),              \
                                     (AS3 void*)(_buf + w*1024),          16, 0, 0); \
    __builtin_amdgcn_global_load_lds((const AS1 void*)(Ag + (step)*32 + 64*DM),      \
                                     (AS3 void*)(_buf + 4096 + w*1024),   16, 0, 0); \
    __builtin_amdgcn_global_load_lds((const AS1 void*)(Bg + (step)*32),              \
                                     (AS3 void*)(_buf + 8192 + w*1024),   16, 0, 0); \
    __builtin_amdgcn_global_load_lds((const AS1 void*)(Bg + (step)*32 + 64*DM),      \
                                     (AS3 void*)(_buf + 12288 + w*1024),  16, 0, 0); \
  } while (0)

  STAGE(0);
  for (int s = 0; s < 32; ++s) {
    if (s < 31) {
      STAGE(s + 1);
      asm volatile("s_waitcnt vmcnt(4)" ::: "memory");
    } else {
      asm volatile("s_waitcnt vmcnt(0)" ::: "memory");
    }
    __builtin_amdgcn_s_barrier();
    __builtin_amdgcn_sched_barrier(0);

    const AS3 unsigned short* bufA =
        (const AS3 unsigned short*)((AS3 char*)smem + (s & 1) * 16384);
    const AS3 unsigned short* bufB = bufA + 4096;
    bf16x8 af[4], bfv[4];
    #pragma unroll
    for (int i = 0; i < 4; ++i)
      af[i] = *(const AS3 bf16x8*)(bufA + (wm + 16*i + cl) * 32 + g*8);
    #pragma unroll
    for (int j = 0; j < 4; ++j)
      bfv[j] = *(const AS3 bf16x8*)(bufB + (wn + 16*j + cl) * 32 + g*8);
    #pragma unroll
    for (int i = 0; i < 4; ++i)
      #pragma unroll
      for (int j = 0; j < 4; ++j)
        acc[i][j] = mfma16(af[i], bfv[j], acc[i][j]);

    __builtin_amdgcn_sched_barrier(0);
    __builtin_amdgcn_s_barrier();
  }
  #undef STAGE

  if (mode == 1) {
    unsigned short* Cs = (unsigned short*)smem;
    __syncthreads();
    #pragma unroll
    for (int i = 0; i < 4; ++i) {
      #pragma unroll
      for (int j = 0; j < 4; ++j) {
        const int n = wn + 16*j + cl;
        const float bn = bias[n0 + n];
        const int u = (wm >> 2) + 4*i + g;
        const int us = u ^ (n & 31);
        u16x4 o;
        #pragma unroll
        for (int r = 0; r < 4; ++r) o[r] = f2bf(acc[i][j][r] + bn);
        *reinterpret_cast<u16x4*>(&Cs[n*128 + us*4]) = o;
      }
    }
    __syncthreads();
    {
      const int n = t >> 1, mh = (t & 1) * 64;
      const int ncol = n0 + n;
      const int h = ncol >> 6, d = ncol & (KDIM-1);
      const int b = m0 >> 11, s0 = m0 & (S_LEN-1);
      unsigned short* drow = (unsigned short*)dst
          + ((size_t)(b*NH + h)*KDIM + d)*S_LEN + s0 + mh;
      #pragma unroll
      for (int mm = 0; mm < 4; ++mm) {
        u16x4 v[4];
        #pragma unroll
        for (int k = 0; k < 4; ++k) {
          const int us = ((mh >> 2) + mm*4 + k) ^ (n & 31);
          v[k] = *reinterpret_cast<const u16x4*>(&Cs[n*128 + us*4]);
        }
        u16x8 w01, w23;
        #pragma unroll
        for (int e = 0; e < 4; ++e) {
          w01[e] = v[0][e]; w01[4+e] = v[1][e];
          w23[e] = v[2][e]; w23[4+e] = v[3][e];
        }
        *reinterpret_cast<u16x8*>(drow + mm*16)     = w01;
        *reinterpret_cast<u16x8*>(drow + mm*16 + 8) = w23;
      }
    }
  } else {
    #pragma unroll
    for (int i = 0; i < 4; ++i)
      #pragma unroll
      for (int j = 0; j < 4; ++j) {
        const int ncol = n0 + wn + 16*j + cl;
        const float bn = bias[ncol];
        #pragma unroll
        for (int r = 0; r < 4; ++r) {
          const int m = m0 + wm + 16*i + g*4 + r;
          const float v = acc[i][j][r] + bn;
          if (mode == 0) {
            const int b = m >> 11, sR = m & (S_LEN-1);
            const int h = ncol >> 6, d = ncol & (KDIM-1);
            ((unsigned short*)dst)[((size_t)(b*NH + h)*S_LEN + sR)*KDIM + d] = f2bf(v);
          } else {
            ((float*)dst)[(size_t)m * DM + ncol] = v;
          }
        }
      }
  }
}

// ---------------------------------------------------------------------------
// Fused attention v9: R7 structure, rebalanced phases.
// Pass A = LEAN sums only: K ring staged by waves 0-3 (vmcnt(6)); waves 4-7
// execute ZERO waits; no LDS writes, no V, no P-pack.
// Pass B = store + PV + ctx: K ring (w0-3) + V ring (w4-7), counted vmcnt
// with 12-store slack (never drained); P packed pre-normalized -> PV gives
// normalized O directly.
// ---------------------------------------------------------------------------
__global__ __launch_bounds__(512, 4)
void attn_fused9(const unsigned short* __restrict__ Qh,
                 const unsigned short* __restrict__ Kh,
                 const unsigned short* __restrict__ Vt,
                 float* __restrict__ attn,
                 unsigned short* __restrict__ ctx)
{
  __shared__ __align__(16) char smem[75776];
  AS3 char* const KB = (AS3 char*)smem;
  AS3 char* const VB = (AS3 char*)smem + 32768;

  const int id  = blockIdx.x;                 // 512 = 8 XCD x 64
  const int swz = (id & 7) * 64 + (id >> 3);  // bijective XCD swizzle
  const int bh  = swz >> 4;                   // head 0..31
  const int q0  = (swz & 15) * 128;           // 128-row q tile

  const int t = threadIdx.x, w = t >> 6, l = t & 63;
  const int g = l >> 4, cl = l & 15;
  AS3 char* const PBw = (AS3 char*)smem + 65536 + w * 1280;
  const int b = bh >> 4, h = bh & 15;

  const unsigned short* Qb = Qh + ((size_t)bh * S_LEN + q0 + w*16 + cl) * KDIM;
  const bf16x8 qf0 = *reinterpret_cast<const bf16x8*>(Qb + g*8);
  const bf16x8 qf1 = *reinterpret_cast<const bf16x8*>(Qb + 32 + g*8);

  const int rs = (w & 3)*8 + (l >> 3), js = l & 7;
  const unsigned short* pK = Kh + (size_t)bh*S_LEN*KDIM + (size_t)rs*KDIM
                                + (size_t)((js ^ (rs & 7)) * 8);
  const int dsv = (w & 3)*16 + (l >> 2), jv = l & 3;
  const int kst = (dsv & 3) ^ ((dsv >> 2) & 3);
  const unsigned short* pV = Vt + (size_t)bh*KDIM*S_LEN + (size_t)dsv*S_LEN
                                + (size_t)((jv ^ kst) * 8);

  const unsigned kvkey = (unsigned)((cl & 3) ^ ((cl >> 2) & 3));
  const unsigned koff0 = (unsigned)(cl*128 + ((g ^ (cl & 7)) << 4));
  const unsigned koff1 = (unsigned)(cl*128 + (((g + 4) ^ (cl & 7)) << 4));
  const float SC2 = 0.125f * 1.44269504f;     // 1/sqrt(64) * log2(e)

  #define STAGE_K(ch) do { int _b = (ch) & 7;                                               \
    if (w < 4) __builtin_amdgcn_global_load_lds((const AS1 void*)(pK + (size_t)(ch)*2048),  \
                   (AS3 void*)(KB + _b*4096 + (w&3)*1024), 16, 0, 0); } while (0)
  #define STAGE_KV(ch) do { int _b = (ch) & 7;                                              \
    if (w < 4) __builtin_amdgcn_global_load_lds((const AS1 void*)(pK + (size_t)(ch)*2048),  \
                   (AS3 void*)(KB + _b*4096 + (w&3)*1024), 16, 0, 0);                       \
    else       __builtin_amdgcn_global_load_lds((const AS1 void*)(pV + (size_t)(ch)*32),    \
                   (AS3 void*)(VB + _b*4096 + (w&3)*1024), 16, 0, 0); } while (0)

  // ================= PASS A: lean row sums (no V, no LDS writes) ===========
  float sa0 = 0.f, sa1 = 0.f, sa2 = 0.f, sa3 = 0.f;

  for (int i = 0; i < 6; ++i) STAGE_K(i);
  for (int c = 0; c < 64; ++c) {
    STAGE_K(c + 6);                              // overrun lands in valid ws
    if (w < 4) asm volatile("s_waitcnt vmcnt(6)" ::: "memory");
    __builtin_amdgcn_s_barrier();
    __builtin_amdgcn_sched_barrier(0);
    AS3 const char* kb = KB + (c & 7) * 4096;
    #pragma unroll
    for (int s = 0; s < 2; ++s) {
      const bf16x8 k0 = *(const AS3 bf16x8*)(kb + s*2048 + koff0);
      const bf16x8 k1 = *(const AS3 bf16x8*)(kb + s*2048 + koff1);
      f32x4 acc = {0.f, 0.f, 0.f, 0.f};
      acc = mfma16(k0, qf0, acc);
      acc = mfma16(k1, qf1, acc);
      sa0 += __builtin_exp2f(acc[0] * SC2);
      sa1 += __builtin_exp2f(acc[1] * SC2);
      sa2 += __builtin_exp2f(acc[2] * SC2);
      sa3 += __builtin_exp2f(acc[3] * SC2);
    }
  }

  float ssum = (sa0 + sa1) + (sa2 + sa3);
  ssum += __shfl_xor(ssum, 16, 64);
  ssum += __shfl_xor(ssum, 32, 64);
  const float inv = 1.0f / ssum;                 // row q = w*16 + cl

  __syncthreads();                               // drain pass A fully

  // ================= PASS B: store + PV + ctx ==============================
  float* const arow = attn + ((size_t)bh * S_LEN + q0 + w*16 + cl) * S_LEN + g*4;
  f32x4 accP[4];
  #pragma unroll
  for (int dt = 0; dt < 4; ++dt) accP[dt] = 0.f;

  for (int i = 0; i < 6; ++i) STAGE_KV(i);
  for (int c = 0; c < 64; ++c) {
    STAGE_KV(c + 6);
    if (c < 6) asm volatile("s_waitcnt vmcnt(6)"  ::: "memory");
    else       asm volatile("s_waitcnt vmcnt(18)" ::: "memory");  // 6 loads + 12-store slack
    __builtin_amdgcn_s_barrier();
    __builtin_amdgcn_sched_barrier(0);
    AS3 const char* kb = KB + (c & 7) * 4096;
    AS3 const char* vb = VB + (c & 7) * 4096;
    #pragma unroll
    for (int s = 0; s < 2; ++s) {
      const bf16x8 k0 = *(const AS3 bf16x8*)(kb + s*2048 + koff0);
      const bf16x8 k1 = *(const AS3 bf16x8*)(kb + s*2048 + koff1);
      f32x4 acc = {0.f, 0.f, 0.f, 0.f};
      acc = mfma16(k0, qf0, acc);
      acc = mfma16(k1, qf1, acc);
      f32x4 p;
      p[0] = __builtin_exp2f(acc[0] * SC2) * inv;
      p[1] = __builtin_exp2f(acc[1] * SC2) * inv;
      p[2] = __builtin_exp2f(acc[2] * SC2) * inv;
      p[3] = __builtin_exp2f(acc[3] * SC2) * inv;
      *reinterpret_cast<f32x4*>(arow + c*32 + s*16) = p;   // streamed fp32 attn
      u16x4 pb;
      pb[0] = f2bf(p[0]); pb[1] = f2bf(p[1]); pb[2] = f2bf(p[2]); pb[3] = f2bf(p[3]);
      *(AS3 u16x4*)(PBw + cl*80 + s*32 + g*8) = pb;
    }
    const bf16x8 ap = *(const AS3 bf16x8*)(PBw + cl*80 + g*16);
    #pragma unroll
    for (int dt = 0; dt < 4; ++dt) {
      const bf16x8 bv = *(const AS3 bf16x8*)(vb + (dt*16 + cl)*64 + ((g ^ kvkey) << 4));
      accP[dt] = mfma16(ap, bv, accP[dt]);       // P pre-normalized
    }
  }
  #undef STAGE_K
  #undef STAGE_KV

  // ctx write: lane holds O[q = g*4+r][d = dt*16+cl] (already normalized)
  #pragma unroll
  for (int r = 0; r < 4; ++r) {
    const size_t row = (size_t)(b * S_LEN + q0 + w*16 + g*4 + r);
    #pragma unroll
    for (int dt = 0; dt < 4; ++dt)
      ctx[row * DM + h * KDIM + dt*16 + cl] = f2bf(accP[dt][r]);
  }
}

// ---------------------------------------------------------------------------
extern "C" void kernel_launch(void* const* d_in, const int* in_sizes, int n_in,
                              void* d_out, int out_size, void* d_ws, size_t ws_size,
                              hipStream_t stream)
{
  const float* q_in = (const float*)d_in[0];
  const float* k_in = (const float*)d_in[1];
  const float* v_in = (const float*)d_in[2];
  const float* Wq   = (const float*)d_in[3];
  const float* bq   = (const float*)d_in[4];
  const float* Wk   = (const float*)d_in[5];
  const float* bk   = (const float*)d_in[6];
  const float* Wv   = (const float*)d_in[7];
  const float* bv   = (const float*)d_in[8];
  const float* Wo   = (const float*)d_in[9];
  const float* bo   = (const float*)d_in[10];

  unsigned short* qbf  = (unsigned short*)d_ws;
  unsigned short* kbf  = qbf  + (size_t)MTOK*DM;
  unsigned short* vbf  = kbf  + (size_t)MTOK*DM;
  unsigned short* wqbf = vbf  + (size_t)MTOK*DM;
  unsigned short* wkbf = wqbf + (size_t)DM*DM;
  unsigned short* wvbf = wkbf + (size_t)DM*DM;
  unsigned short* wobf = wvbf + (size_t)DM*DM;
  unsigned short* Qhp  = wobf + (size_t)DM*DM;    // [b,h,s,d]
  unsigned short* Khp  = Qhp  + (size_t)MTOK*DM;  // [b,h,s,d]
  unsigned short* Vtp  = Khp  + (size_t)MTOK*DM;  // [b,h,d,s]
  unsigned short* ctx  = Vtp  + (size_t)MTOK*DM;  // [b*s, h*d]

  float* out0 = (float*)d_out;
  float* attn = out0 + (size_t)MTOK*DM;

  CvtArgs ca;
  ca.src[0] = q_in; ca.dst[0] = qbf;  ca.n[0] = MTOK*DM;
  ca.src[1] = k_in; ca.dst[1] = kbf;  ca.n[1] = MTOK*DM;
  ca.src[2] = v_in; ca.dst[2] = vbf;  ca.n[2] = MTOK*DM;
  ca.src[3] = Wq;   ca.dst[3] = wqbf; ca.n[3] = DM*DM;
  ca.src[4] = Wk;   ca.dst[4] = wkbf; ca.n[4] = DM*DM;
  ca.src[5] = Wv;   ca.dst[5] = wvbf; ca.n[5] = DM*DM;
  ca.src[6] = Wo;   ca.dst[6] = wobf; ca.n[6] = DM*DM;
  cvt_f32_bf16<<<dim3(512, 7), 256, 0, stream>>>(ca);

  GemmArgs gq;
  gq.A[0] = qbf;  gq.W[0] = wqbf; gq.bias[0] = bq; gq.dst[0] = Qhp; gq.mode[0] = 0;
  gq.A[1] = kbf;  gq.W[1] = wkbf; gq.bias[1] = bk; gq.dst[1] = Khp; gq.mode[1] = 0;
  gq.A[2] = vbf;  gq.W[2] = wvbf; gq.bias[2] = bv; gq.dst[2] = Vtp; gq.mode[2] = 1;
  gemm_pipe<<<dim3(8, 32, 3), 256, 0, stream>>>(gq);

  attn_fused9<<<dim3(512), 512, 0, stream>>>(Qhp, Khp, Vtp, attn, ctx);

  GemmArgs go;
  go.A[0] = ctx; go.W[0] = wobf; go.bias[0] = bo; go.dst[0] = out0; go.mode[0] = 2;
  gemm_pipe<<<dim3(8, 32, 1), 256, 0, stream>>>(go);
}

// Round 14
// 268.198 us; speedup vs baseline: 1.6424x; 1.0368x over previous
//
#include <hip/hip_runtime.h>
#include <hip/hip_bf16.h>
#include <stdint.h>

#define S_LEN 2048
#define NB 2
#define NH 16
#define DM 1024
#define KDIM 64
#define MTOK (NB*S_LEN)   // 4096 tokens

typedef __attribute__((ext_vector_type(8))) short bf16x8;
typedef __attribute__((ext_vector_type(4))) float f32x4;
typedef __attribute__((ext_vector_type(4))) unsigned short u16x4;
typedef __attribute__((ext_vector_type(8))) unsigned short u16x8;

#define AS1 __attribute__((address_space(1)))
#define AS3 __attribute__((address_space(3)))

__device__ __forceinline__ unsigned short f2bf(float f) {
  unsigned int u = __builtin_bit_cast(unsigned int, f);
  return (unsigned short)((u + 0x7fffu + ((u >> 16) & 1u)) >> 16);   // RNE
}
__device__ __forceinline__ f32x4 mfma16(bf16x8 a, bf16x8 b, f32x4 c) {
  return __builtin_amdgcn_mfma_f32_16x16x32_bf16(a, b, c, 0, 0, 0);
}

// ---------------------------------------------------------------------------
// fp32 -> bf16 convert, 7 segments
// ---------------------------------------------------------------------------
struct CvtArgs {
  const float* src[7];
  unsigned short* dst[7];
  int n[7];
};

__global__ __launch_bounds__(256) void cvt_f32_bf16(CvtArgs a) {
  const int seg = blockIdx.y;
  const float* __restrict__ s = a.src[seg];
  unsigned short* __restrict__ d = a.dst[seg];
  const int n4 = a.n[seg] >> 2;
  const int stride = gridDim.x * blockDim.x;
  for (int i = blockIdx.x * blockDim.x + threadIdx.x; i < n4; i += stride) {
    const float4 v = reinterpret_cast<const float4*>(s)[i];
    u16x4 o;
    o[0] = f2bf(v.x); o[1] = f2bf(v.y); o[2] = f2bf(v.z); o[3] = f2bf(v.w);
    reinterpret_cast<u16x4*>(d)[i] = o;
  }
}

// ---------------------------------------------------------------------------
// Pipelined GEMM (R9-verified) + XCD-local m-tile remap (R11/R13).
// ---------------------------------------------------------------------------
struct GemmArgs {
  const unsigned short* A[3];
  const unsigned short* W[3];
  const float* bias[3];
  void* dst[3];
  int mode[3];
};

__global__ __launch_bounds__(256, 2)
void gemm_pipe(GemmArgs ga)
{
  __shared__ __align__(16) char smem[32768];   // 2 x (A 8K + B 8K); Cs union

  const int z = blockIdx.z;
  const unsigned short* __restrict__ A  = ga.A[z];
  const unsigned short* __restrict__ Bw = ga.W[z];
  const float* __restrict__ bias = ga.bias[z];
  void* __restrict__ dst = ga.dst[z];
  const int mode = ga.mode[z];

  const int t = threadIdx.x;
  const int w = t >> 6, l = t & 63;
  const int g = l >> 4, cl = l & 15;

  const int L   = blockIdx.x + 8 * blockIdx.y;   // 0..255
  const int xcd = L & 7, ix = L >> 3;
  const int m0  = (xcd * 4 + (ix & 3)) * 128;
  const int n0  = (ix >> 2) * 128;

  const unsigned short* Ag = A  + (size_t)(m0 + (t >> 2)) * DM + (t & 3) * 8;
  const unsigned short* Bg = Bw + (size_t)(n0 + (t >> 2)) * DM + (t & 3) * 8;

  const int wm = (w >> 1) * 64, wn = (w & 1) * 64;

  f32x4 acc[4][4];
  #pragma unroll
  for (int i = 0; i < 4; ++i)
    #pragma unroll
    for (int j = 0; j < 4; ++j) acc[i][j] = 0.f;

  #define STAGE(step) do {                                                          \
    AS3 char* _buf = (AS3 char*)smem + ((step) & 1) * 16384;                         \
    __builtin_amdgcn_global_load_lds((const AS1 void*)(Ag + (step)*32),              \
                                     (AS3 void*)(_buf + w*1024),          16, 0, 0); \
    __builtin_amdgcn_global_load_lds((const AS1 void*)(Ag + (step)*32 + 64*DM),      \
                                     (AS3 void*)(_buf + 4096 + w*1024),   16, 0, 0); \
    __builtin_amdgcn_global_load_lds((const AS1 void*)(Bg + (step)*32),              \
                                     (AS3 void*)(_buf + 8192 + w*1024),   16, 0, 0); \
    __builtin_amdgcn_global_load_lds((const AS1 void*)(Bg + (step)*32 + 64*DM),      \
                                     (AS3 void*)(_buf + 12288 + w*1024),  16, 0, 0); \
  } while (0)

  STAGE(0);
  for (int s = 0; s < 32; ++s) {
    if (s < 31) {
      STAGE(s + 1);
      asm volatile("s_waitcnt vmcnt(4)" ::: "memory");
    } else {
      asm volatile("s_waitcnt vmcnt(0)" ::: "memory");
    }
    __builtin_amdgcn_s_barrier();
    __builtin_amdgcn_sched_barrier(0);

    const AS3 unsigned short* bufA =
        (const AS3 unsigned short*)((AS3 char*)smem + (s & 1) * 16384);
    const AS3 unsigned short* bufB = bufA + 4096;
    bf16x8 af[4], bfv[4];
    #pragma unroll
    for (int i = 0; i < 4; ++i)
      af[i] = *(const AS3 bf16x8*)(bufA + (wm + 16*i + cl) * 32 + g*8);
    #pragma unroll
    for (int j = 0; j < 4; ++j)
      bfv[j] = *(const AS3 bf16x8*)(bufB + (wn + 16*j + cl) * 32 + g*8);
    #pragma unroll
    for (int i = 0; i < 4; ++i)
      #pragma unroll
      for (int j = 0; j < 4; ++j)
        acc[i][j] = mfma16(af[i], bfv[j], acc[i][j]);

    __builtin_amdgcn_sched_barrier(0);
    __builtin_amdgcn_s_barrier();
  }
  #undef STAGE

  if (mode == 1) {
    unsigned short* Cs = (unsigned short*)smem;
    __syncthreads();
    #pragma unroll
    for (int i = 0; i < 4; ++i) {
      #pragma unroll
      for (int j = 0; j < 4; ++j) {
        const int n = wn + 16*j + cl;
        const float bn = bias[n0 + n];
        const int u = (wm >> 2) + 4*i + g;
        const int us = u ^ (n & 31);
        u16x4 o;
        #pragma unroll
        for (int r = 0; r < 4; ++r) o[r] = f2bf(acc[i][j][r] + bn);
        *reinterpret_cast<u16x4*>(&Cs[n*128 + us*4]) = o;
      }
    }
    __syncthreads();
    {
      const int n = t >> 1, mh = (t & 1) * 64;
      const int ncol = n0 + n;
      const int h = ncol >> 6, d = ncol & (KDIM-1);
      const int b = m0 >> 11, s0 = m0 & (S_LEN-1);
      unsigned short* drow = (unsigned short*)dst
          + ((size_t)(b*NH + h)*KDIM + d)*S_LEN + s0 + mh;
      #pragma unroll
      for (int mm = 0; mm < 4; ++mm) {
        u16x4 v[4];
        #pragma unroll
        for (int k = 0; k < 4; ++k) {
          const int us = ((mh >> 2) + mm*4 + k) ^ (n & 31);
          v[k] = *reinterpret_cast<const u16x4*>(&Cs[n*128 + us*4]);
        }
        u16x8 w01, w23;
        #pragma unroll
        for (int e = 0; e < 4; ++e) {
          w01[e] = v[0][e]; w01[4+e] = v[1][e];
          w23[e] = v[2][e]; w23[4+e] = v[3][e];
        }
        *reinterpret_cast<u16x8*>(drow + mm*16)     = w01;
        *reinterpret_cast<u16x8*>(drow + mm*16 + 8) = w23;
      }
    }
  } else {
    #pragma unroll
    for (int i = 0; i < 4; ++i)
      #pragma unroll
      for (int j = 0; j < 4; ++j) {
        const int ncol = n0 + wn + 16*j + cl;
        const float bn = bias[ncol];
        #pragma unroll
        for (int r = 0; r < 4; ++r) {
          const int m = m0 + wm + 16*i + g*4 + r;
          const float v = acc[i][j][r] + bn;
          if (mode == 0) {
            const int b = m >> 11, sR = m & (S_LEN-1);
            const int h = ncol >> 6, d = ncol & (KDIM-1);
            ((unsigned short*)dst)[((size_t)(b*NH + h)*S_LEN + sR)*KDIM + d] = f2bf(v);
          } else {
            ((float*)dst)[(size_t)m * DM + ncol] = v;
          }
        }
      }
  }
}

// ---------------------------------------------------------------------------
// Fused attention v10: R13 structure with 2 chunks (64 kv) per barrier
// section (32 sections/pass instead of 64). Ring-safety: vmcnt -> barrier ->
// stage -> compute (staged slots' previous readers are provably past the
// barrier). Pass A = lean sums (vmcnt(4)); pass B = store+PV+ctx
// (vmcnt(16) steady = 4 loads + 12-store slack; never drained).
// ---------------------------------------------------------------------------
__global__ __launch_bounds__(512, 4)
void attn_fused10(const unsigned short* __restrict__ Qh,
                  const unsigned short* __restrict__ Kh,
                  const unsigned short* __restrict__ Vt,
                  float* __restrict__ attn,
                  unsigned short* __restrict__ ctx)
{
  __shared__ __align__(16) char smem[75776];
  AS3 char* const KB = (AS3 char*)smem;
  AS3 char* const VB = (AS3 char*)smem + 32768;

  const int id  = blockIdx.x;                 // 512 = 8 XCD x 64
  const int swz = (id & 7) * 64 + (id >> 3);  // bijective XCD swizzle
  const int bh  = swz >> 4;                   // head 0..31
  const int q0  = (swz & 15) * 128;           // 128-row q tile

  const int t = threadIdx.x, w = t >> 6, l = t & 63;
  const int g = l >> 4, cl = l & 15;
  AS3 char* const PBw = (AS3 char*)smem + 65536 + w * 1280;
  const int b = bh >> 4, h = bh & 15;

  const unsigned short* Qb = Qh + ((size_t)bh * S_LEN + q0 + w*16 + cl) * KDIM;
  const bf16x8 qf0 = *reinterpret_cast<const bf16x8*>(Qb + g*8);
  const bf16x8 qf1 = *reinterpret_cast<const bf16x8*>(Qb + 32 + g*8);

  const int rs = (w & 3)*8 + (l >> 3), js = l & 7;
  const unsigned short* pK = Kh + (size_t)bh*S_LEN*KDIM + (size_t)rs*KDIM
                                + (size_t)((js ^ (rs & 7)) * 8);
  const int dsv = (w & 3)*16 + (l >> 2), jv = l & 3;
  const int kst = (dsv & 3) ^ ((dsv >> 2) & 3);
  const unsigned short* pV = Vt + (size_t)bh*KDIM*S_LEN + (size_t)dsv*S_LEN
                                + (size_t)((jv ^ kst) * 8);

  const unsigned kvkey = (unsigned)((cl & 3) ^ ((cl >> 2) & 3));
  const unsigned koff0 = (unsigned)(cl*128 + ((g ^ (cl & 7)) << 4));
  const unsigned koff1 = (unsigned)(cl*128 + (((g + 4) ^ (cl & 7)) << 4));
  const float SC2 = 0.125f * 1.44269504f;     // 1/sqrt(64) * log2(e)

  #define STAGE_K(ch) do { int _b = (ch) & 7;                                               \
    if (w < 4) __builtin_amdgcn_global_load_lds((const AS1 void*)(pK + (size_t)(ch)*2048),  \
                   (AS3 void*)(KB + _b*4096 + (w&3)*1024), 16, 0, 0); } while (0)
  #define STAGE_KV(ch) do { int _b = (ch) & 7;                                              \
    if (w < 4) __builtin_amdgcn_global_load_lds((const AS1 void*)(pK + (size_t)(ch)*2048),  \
                   (AS3 void*)(KB + _b*4096 + (w&3)*1024), 16, 0, 0);                       \
    else       __builtin_amdgcn_global_load_lds((const AS1 void*)(pV + (size_t)(ch)*32),    \
                   (AS3 void*)(VB + _b*4096 + (w&3)*1024), 16, 0, 0); } while (0)

  // ================= PASS A: lean row sums, 32 sections x 64 kv ============
  float sa0 = 0.f, sa1 = 0.f, sa2 = 0.f, sa3 = 0.f;

  for (int i = 0; i < 6; ++i) STAGE_K(i);
  for (int k = 0; k < 32; ++k) {
    const int c = 2 * k;
    if (w < 4) asm volatile("s_waitcnt vmcnt(4)" ::: "memory");  // c, c+1 landed
    __builtin_amdgcn_s_barrier();
    __builtin_amdgcn_sched_barrier(0);
    STAGE_K(c + 6);                              // overwritten slots read 2 sections ago
    STAGE_K(c + 7);                              // (barrier above guarantees done)
    #pragma unroll
    for (int cc = 0; cc < 2; ++cc) {
      AS3 const char* kb = KB + ((c + cc) & 7) * 4096;
      #pragma unroll
      for (int s = 0; s < 2; ++s) {
        const bf16x8 k0 = *(const AS3 bf16x8*)(kb + s*2048 + koff0);
        const bf16x8 k1 = *(const AS3 bf16x8*)(kb + s*2048 + koff1);
        f32x4 acc = {0.f, 0.f, 0.f, 0.f};
        acc = mfma16(k0, qf0, acc);
        acc = mfma16(k1, qf1, acc);
        sa0 += __builtin_exp2f(acc[0] * SC2);
        sa1 += __builtin_exp2f(acc[1] * SC2);
        sa2 += __builtin_exp2f(acc[2] * SC2);
        sa3 += __builtin_exp2f(acc[3] * SC2);
      }
    }
  }

  float ssum = (sa0 + sa1) + (sa2 + sa3);
  ssum += __shfl_xor(ssum, 16, 64);
  ssum += __shfl_xor(ssum, 32, 64);
  const float inv = 1.0f / ssum;                 // row q = w*16 + cl

  __syncthreads();                               // drain pass A fully

  // ================= PASS B: store + PV + ctx, 32 sections =================
  float* const arow = attn + ((size_t)bh * S_LEN + q0 + w*16 + cl) * S_LEN + g*4;
  f32x4 accP[4];
  #pragma unroll
  for (int dt = 0; dt < 4; ++dt) accP[dt] = 0.f;

  for (int i = 0; i < 6; ++i) STAGE_KV(i);
  for (int k = 0; k < 32; ++k) {
    const int c = 2 * k;
    if (k < 3) asm volatile("s_waitcnt vmcnt(4)"  ::: "memory");
    else       asm volatile("s_waitcnt vmcnt(16)" ::: "memory");  // 4 loads + 12-store slack
    __builtin_amdgcn_s_barrier();
    __builtin_amdgcn_sched_barrier(0);
    STAGE_KV(c + 6);
    STAGE_KV(c + 7);
    #pragma unroll
    for (int cc = 0; cc < 2; ++cc) {
      const int ch = c + cc;
      AS3 const char* kb = KB + (ch & 7) * 4096;
      AS3 const char* vb = VB + (ch & 7) * 4096;
      #pragma unroll
      for (int s = 0; s < 2; ++s) {
        const bf16x8 k0 = *(const AS3 bf16x8*)(kb + s*2048 + koff0);
        const bf16x8 k1 = *(const AS3 bf16x8*)(kb + s*2048 + koff1);
        f32x4 acc = {0.f, 0.f, 0.f, 0.f};
        acc = mfma16(k0, qf0, acc);
        acc = mfma16(k1, qf1, acc);
        f32x4 p;
        p[0] = __builtin_exp2f(acc[0] * SC2) * inv;
        p[1] = __builtin_exp2f(acc[1] * SC2) * inv;
        p[2] = __builtin_exp2f(acc[2] * SC2) * inv;
        p[3] = __builtin_exp2f(acc[3] * SC2) * inv;
        *reinterpret_cast<f32x4*>(arow + ch*32 + s*16) = p;   // streamed fp32 attn
        u16x4 pb;
        pb[0] = f2bf(p[0]); pb[1] = f2bf(p[1]); pb[2] = f2bf(p[2]); pb[3] = f2bf(p[3]);
        *(AS3 u16x4*)(PBw + cl*80 + s*32 + g*8) = pb;
      }
      const bf16x8 ap = *(const AS3 bf16x8*)(PBw + cl*80 + g*16);
      #pragma unroll
      for (int dt = 0; dt < 4; ++dt) {
        const bf16x8 bv = *(const AS3 bf16x8*)(vb + (dt*16 + cl)*64 + ((g ^ kvkey) << 4));
        accP[dt] = mfma16(ap, bv, accP[dt]);     // P pre-normalized
      }
    }
  }
  #undef STAGE_K
  #undef STAGE_KV

  // ctx write: lane holds O[q = g*4+r][d = dt*16+cl] (already normalized)
  #pragma unroll
  for (int r = 0; r < 4; ++r) {
    const size_t row = (size_t)(b * S_LEN + q0 + w*16 + g*4 + r);
    #pragma unroll
    for (int dt = 0; dt < 4; ++dt)
      ctx[row * DM + h * KDIM + dt*16 + cl] = f2bf(accP[dt][r]);
  }
}

// ---------------------------------------------------------------------------
extern "C" void kernel_launch(void* const* d_in, const int* in_sizes, int n_in,
                              void* d_out, int out_size, void* d_ws, size_t ws_size,
                              hipStream_t stream)
{
  const float* q_in = (const float*)d_in[0];
  const float* k_in = (const float*)d_in[1];
  const float* v_in = (const float*)d_in[2];
  const float* Wq   = (const float*)d_in[3];
  const float* bq   = (const float*)d_in[4];
  const float* Wk   = (const float*)d_in[5];
  const float* bk   = (const float*)d_in[6];
  const float* Wv   = (const float*)d_in[7];
  const float* bv   = (const float*)d_in[8];
  const float* Wo   = (const float*)d_in[9];
  const float* bo   = (const float*)d_in[10];

  unsigned short* qbf  = (unsigned short*)d_ws;
  unsigned short* kbf  = qbf  + (size_t)MTOK*DM;
  unsigned short* vbf  = kbf  + (size_t)MTOK*DM;
  unsigned short* wqbf = vbf  + (size_t)MTOK*DM;
  unsigned short* wkbf = wqbf + (size_t)DM*DM;
  unsigned short* wvbf = wkbf + (size_t)DM*DM;
  unsigned short* wobf = wvbf + (size_t)DM*DM;
  unsigned short* Qhp  = wobf + (size_t)DM*DM;    // [b,h,s,d]
  unsigned short* Khp  = Qhp  + (size_t)MTOK*DM;  // [b,h,s,d]
  unsigned short* Vtp  = Khp  + (size_t)MTOK*DM;  // [b,h,d,s]
  unsigned short* ctx  = Vtp  + (size_t)MTOK*DM;  // [b*s, h*d]

  float* out0 = (float*)d_out;
  float* attn = out0 + (size_t)MTOK*DM;

  CvtArgs ca;
  ca.src[0] = q_in; ca.dst[0] = qbf;  ca.n[0] = MTOK*DM;
  ca.src[1] = k_in; ca.dst[1] = kbf;  ca.n[1] = MTOK*DM;
  ca.src[2] = v_in; ca.dst[2] = vbf;  ca.n[2] = MTOK*DM;
  ca.src[3] = Wq;   ca.dst[3] = wqbf; ca.n[3] = DM*DM;
  ca.src[4] = Wk;   ca.dst[4] = wkbf; ca.n[4] = DM*DM;
  ca.src[5] = Wv;   ca.dst[5] = wvbf; ca.n[5] = DM*DM;
  ca.src[6] = Wo;   ca.dst[6] = wobf; ca.n[6] = DM*DM;
  cvt_f32_bf16<<<dim3(512, 7), 256, 0, stream>>>(ca);

  GemmArgs gq;
  gq.A[0] = qbf;  gq.W[0] = wqbf; gq.bias[0] = bq; gq.dst[0] = Qhp; gq.mode[0] = 0;
  gq.A[1] = kbf;  gq.W[1] = wkbf; gq.bias[1] = bk; gq.dst[1] = Khp; gq.mode[1] = 0;
  gq.A[2] = vbf;  gq.W[2] = wvbf; gq.bias[2] = bv; gq.dst[2] = Vtp; gq.mode[2] = 1;
  gemm_pipe<<<dim3(8, 32, 3), 256, 0, stream>>>(gq);

  attn_fused10<<<dim3(512), 512, 0, stream>>>(Qhp, Khp, Vtp, attn, ctx);

  GemmArgs go;
  go.A[0] = ctx; go.W[0] = wobf; go.bias[0] = bo; go.dst[0] = out0; go.mode[0] = 2;
  gemm_pipe<<<dim3(8, 32, 1), 256, 0, stream>>>(go);
}